// Round 4
// baseline (484.633 us; speedup 1.0000x reference)
//
#include <hip/hip_runtime.h>

typedef unsigned short u16;
typedef float f32x4 __attribute__((ext_vector_type(4)));
typedef __bf16 bf16x8 __attribute__((ext_vector_type(8)));

#define S_LEN 2048
#define DM 2048
#define NHEAD 32
#define DHEAD 64

__device__ __forceinline__ u16 f2bf(float f) {
    __bf16 b = (__bf16)f;
    return __builtin_bit_cast(u16, b);
}
__device__ __forceinline__ float bf2f(u16 u) {
    return (float)__builtin_bit_cast(__bf16, u);
}
// async global->LDS, 16B per lane. LDS dest must be wave-uniform base + lane*16.
__device__ __forceinline__ void async16(const void* g, void* l) {
    __builtin_amdgcn_global_load_lds(
        (const __attribute__((address_space(1))) unsigned int*)g,
        (__attribute__((address_space(3))) unsigned int*)l, 16, 0, 0);
}
// hardware sin/cos: v_sin/v_cos take revolutions; fract-reduce first (ISA §3)
__device__ __forceinline__ void fast_sincos(float th, float* s, float* c) {
    float rev = th * 0.15915494309189535f;   // 1/(2*pi)
    rev = rev - floorf(rev);
    *s = __builtin_amdgcn_sinf(rev);
    *c = __builtin_amdgcn_cosf(rev);
}
__device__ __forceinline__ float fexp2(float x) { return __builtin_amdgcn_exp2f(x); }

// ---------------- fused cast f32 -> bf16 for x + 4 weights (one dispatch) ----------------
__global__ __launch_bounds__(256) void cast_all(const float* __restrict__ x,
                                                const float* __restrict__ Wq,
                                                const float* __restrict__ Wk,
                                                const float* __restrict__ Wv,
                                                const float* __restrict__ Wo,
                                                u16* __restrict__ xb,
                                                u16* __restrict__ Wqkv,
                                                u16* __restrict__ Wob) {
    int bid = blockIdx.x;
    const float* src;
    u16* dst;
    long long off;
    if (bid < 8192)       { src = x;  dst = xb;             off = (long long)bid * 1024; }
    else if (bid < 12288) { src = Wq; dst = Wqkv;           off = (long long)(bid - 8192) * 1024; }
    else if (bid < 16384) { src = Wk; dst = Wqkv + 4194304; off = (long long)(bid - 12288) * 1024; }
    else if (bid < 20480) { src = Wv; dst = Wqkv + 8388608; off = (long long)(bid - 16384) * 1024; }
    else                  { src = Wo; dst = Wob;            off = (long long)(bid - 20480) * 1024; }
    long long i = off + threadIdx.x * 4;
    float4 f = *(const float4*)(src + i);
    ushort4 v;
    v.x = f2bf(f.x); v.y = f2bf(f.y); v.z = f2bf(f.z); v.w = f2bf(f.w);
    *(ushort4*)(dst + i) = v;
}

// ---- merged aux pass: RoPE on Q (exp2-scale folded) & K, plus sigmoid(V) transpose ----
// blocks 0..32767: rope elementwise; blocks 32768..34815: vsigt tile transpose
__global__ __launch_bounds__(256) void rope_vsig(u16* __restrict__ Qb, u16* __restrict__ Kb,
                                                 const u16* __restrict__ V,
                                                 u16* __restrict__ VT) {
    int bid = blockIdx.x;
    if (bid < 32768) {
        long long idx = (long long)bid * 256 + threadIdx.x;   // 2 * 2^22
        int which = (int)(idx >> 22);
        int t = (int)(idx & 4194303);
        int j = t & 31;
        int h = (t >> 5) & 31;
        int row = t >> 10;                  // 0..4095
        int s = row & (S_LEN - 1);
        u16* T = which ? Kb : Qb;
        float scale = which ? 1.0f : 0.18033688011112042f;  // Q: 1/8 * log2(e)
        long long base = (long long)row * DM + h * DHEAD;
        float inv = __expf(-(float)j * 0.28782313662425575f);  // ln(1e4)/32
        float sn, cs;
        fast_sincos((float)s * inv, &sn, &cs);
        float x1 = bf2f(T[base + j]);
        float x2 = bf2f(T[base + 32 + j]);
        T[base + j] = f2bf((x1 * cs - x2 * sn) * scale);
        T[base + 32 + j] = f2bf((x2 * cs + x1 * sn) * scale);
    } else {
        int vb = bid - 32768;
        int st = vb & 63;        // 64-row s-tile over 4096 rows
        int h = vb >> 6;         // head
        __shared__ u16 T[64][72];
        int r = threadIdx.x >> 2, c0 = (threadIdx.x & 3) * 16;
        const u16* src = V + (long long)(st * 64 + r) * DM + h * 64 + c0;
#pragma unroll
        for (int half = 0; half < 2; ++half) {
            bf16x8 v = *(const bf16x8*)(src + half * 8);
#pragma unroll
            for (int j = 0; j < 8; ++j) {
                float vf = (float)v[j];
                T[c0 + half * 8 + j][r] = f2bf(1.f / (1.f + __expf(-vf)));
            }
        }
        __syncthreads();
        int d = threadIdx.x >> 2, s0 = (threadIdx.x & 3) * 16;
        int b = st >> 5;
        int sl = (st & 31) * 64;
        u16* dst = VT + ((long long)((b * NHEAD + h) * DHEAD + d)) * S_LEN + sl + s0;
#pragma unroll
        for (int q = 0; q < 4; ++q)
            *(ushort4*)(dst + q * 4) = *(const ushort4*)(&T[d][s0] + q * 4);
    }
}

// ---------------- merged QKV GEMM, 256x256 tile, BK=32, DEPTH-3 fragment-major LDS ------
// A[4096][2048] x Wqkv[6144][2048]^T.
// LDS layout: FRAGMENT-MAJOR (R3: zero bank conflicts, verified by PMC). Each 16x32
// fragment is one contiguous 1KB block; every wave-wide ds_read_b128 is base+lane*16.
// R3 finding: LDS path is NOT the critical path (conflicted R1 == clean R3 == 163us).
// R4 change: pipeline depth 2 -> 3. Stage tile t+3 during tile t; 12 loads in flight;
// vmcnt(8) at tile boundary retires planes issued 3 tiles (~6 phases) earlier, putting
// issue->wait distance far above HBM/L2 queueing latency. Ledger: enter tile t with 8
// outstanding {t+1,t+2}; +2 per phase; vmcnt(8) retires exactly {A,B}(t+1). Tail steps
// 8->4->0. sched_barrier(0) after each lgkmcnt(0) (rule #18); setprio around MFMA (T5).
__global__ __launch_bounds__(512, 2) void gemm_qkv8(const u16* __restrict__ A,
                                                    const u16* __restrict__ Bt,
                                                    const float* __restrict__ bq,
                                                    const float* __restrict__ bk,
                                                    const float* __restrict__ bv,
                                                    u16* __restrict__ Qo, u16* __restrict__ Ko,
                                                    u16* __restrict__ Vo) {
    constexpr int K = 2048;
    constexpr int NT = 64;                         // K / 32
    __shared__ __align__(16) u16 Asm[4 * 8192];    // 4 bufs x 16KB, fragment-major
    __shared__ __align__(16) u16 Bsm[4 * 8192];

    int tid = threadIdx.x;
    int w = tid >> 6, lane = tid & 63, quad = lane >> 4, l16 = lane & 15;

    // XCD swizzle: 384 = 8*48 blocks; each XCD gets an m-major chunk of 48 tiles
    // covering 3 consecutive N-panels (3MB of B -> L2-resident per XCD).
    int bid = blockIdx.x;
    int wgid = (bid & 7) * 48 + (bid >> 3);
    int mtile = wgid & 15;                         // 16 M tiles
    int ntile = wgid >> 4;                         // 24 N tiles

    int m0 = mtile * 256;
    int n0g = ntile * 256;
    int sel = n0g >> 11;
    int nloc = n0g & 2047;
    u16* out = sel == 0 ? Qo : (sel == 1 ? Ko : Vo);
    const float* bias = sel == 0 ? bq : (sel == 1 ? bk : bv);

    const u16* ga = A + (long long)m0 * K;
    const u16* gb = Bt + (long long)n0g * K;

    // staging: unit u = tid + r*512; frag = u>>6 (wave-uniform), row = frag*16 + l16,
    // kslot = quad. Per-lane global elem offset = row*K + kslot*8 (+ kt*32).
    long long soff0 = (long long)(((tid >> 6) << 4) + l16) * K + quad * 8;          // r=0
    long long soff1 = (long long)(((((tid + 512) >> 6)) << 4) + l16) * K + quad * 8; // r=1

    auto stageA = [&](int kt, int bufo) {
        async16(ga + soff0 + kt * 32, (char*)(Asm + bufo) + tid * 16);
        async16(ga + soff1 + kt * 32, (char*)(Asm + bufo) + (tid + 512) * 16);
    };
    auto stageB = [&](int kt, int bufo) {
        async16(gb + soff0 + kt * 32, (char*)(Bsm + bufo) + tid * 16);
        async16(gb + soff1 + kt * 32, (char*)(Bsm + bufo) + (tid + 512) * 16);
    };

    int fA = (w >> 2) * 8;        // A frag base: waves 0-3 rows 0-127, waves 4-7 rows 128-255
    int fB = (w & 3) * 4;         // B frag base: wn = (w&3)*64

    f32x4 acc[8][4] = {};
    bf16x8 af[4], bfr[4];

    auto rdA = [&](const u16* Ap, int mh) {
#pragma unroll
        for (int mt = 0; mt < 4; ++mt)
            af[mt] = *(const bf16x8*)(Ap + (fA + mh * 4 + mt) * 512 + lane * 8);
    };
    auto rdB = [&](const u16* Bp) {
#pragma unroll
        for (int nt = 0; nt < 4; ++nt)
            bfr[nt] = *(const bf16x8*)(Bp + (fB + nt) * 512 + lane * 8);
    };
    auto mm = [&](int mh) {
        __builtin_amdgcn_s_setprio(1);
#pragma unroll
        for (int mt = 0; mt < 4; ++mt)
#pragma unroll
            for (int nt = 0; nt < 4; ++nt)
                acc[mh * 4 + mt][nt] = __builtin_amdgcn_mfma_f32_16x16x32_bf16(
                    af[mt], bfr[nt], acc[mh * 4 + mt][nt], 0, 0, 0);
        __builtin_amdgcn_s_setprio(0);
    };

    // prologue: stage tiles 0,1,2 (12 loads); retire tile 0 (oldest 4), keep 8 in flight
    stageA(0, 0);
    stageB(0, 0);
    stageA(1, 8192);
    stageB(1, 8192);
    stageA(2, 16384);
    stageB(2, 16384);
    asm volatile("s_waitcnt vmcnt(8)" ::: "memory");
    __builtin_amdgcn_s_barrier();

#pragma unroll 1
    for (int t = 0; t < NT; ++t) {
        const u16* Ap = Asm + ((t & 3) << 13);
        const u16* Bp = Bsm + ((t & 3) << 13);
        int nbuf = ((t + 3) & 3) << 13;
        // phase 0: issue A(t+3) stage first (longest latency), then LDS reads
        if (t < NT - 3) stageA(t + 3, nbuf);
        rdB(Bp);
        rdA(Ap, 0);
        __builtin_amdgcn_s_barrier();
        asm volatile("s_waitcnt lgkmcnt(0)" ::: "memory");
        __builtin_amdgcn_sched_barrier(0);
        mm(0);
        __builtin_amdgcn_s_barrier();
        // phase 1: issue B(t+3) stage, LDS reads for m-high
        if (t < NT - 3) stageB(t + 3, nbuf);
        rdA(Ap, 1);
        __builtin_amdgcn_s_barrier();
        asm volatile("s_waitcnt lgkmcnt(0)" ::: "memory");
        __builtin_amdgcn_sched_barrier(0);
        mm(1);
        // tile boundary: retire exactly tile t+1's 4 planes (issued 3 tiles ago);
        // tail steps the count down 8 -> 4 -> 0, all block-uniform
        if (t < NT - 3)
            asm volatile("s_waitcnt vmcnt(8)" ::: "memory");
        else if (t == NT - 3)
            asm volatile("s_waitcnt vmcnt(4)" ::: "memory");
        else if (t == NT - 2)
            asm volatile("s_waitcnt vmcnt(0)" ::: "memory");
        __builtin_amdgcn_s_barrier();
    }

    // epilogue: bias + bf16 store (16-lane groups write 32B contiguous)
#pragma unroll
    for (int mf = 0; mf < 8; ++mf) {
#pragma unroll
        for (int nt = 0; nt < 4; ++nt) {
            int col = nloc + (w & 3) * 64 + nt * 16 + l16;
            float bvs = bias[col];
#pragma unroll
            for (int r = 0; r < 4; ++r) {
                int row = m0 + (w >> 2) * 128 + mf * 16 + quad * 4 + r;
                out[(long long)row * 2048 + col] = f2bf(acc[mf][nt][r] + bvs);
            }
        }
    }
}

// ---------------- GEMM: C[M][N] = A[M][K] * Bt[N][K]^T + bias (f32 out) ----------------
__global__ __launch_bounds__(256) void gemm_bt_f32(const u16* __restrict__ A,
                                                   const u16* __restrict__ Bt,
                                                   const float* __restrict__ bias,
                                                   float* __restrict__ Cout,
                                                   int M, int N, int K) {
    __shared__ __align__(16) u16 As[128 * 32];
    __shared__ __align__(16) u16 Bs[128 * 32];
    int tid = threadIdx.x;
    int w = tid >> 6, lane = tid & 63, quad = lane >> 4, l16 = lane & 15;
    int m0 = blockIdx.x * 128;
    int n0 = blockIdx.y * 128;
    int wm = (w & 1) * 64, wn = (w >> 1) * 64;

    f32x4 acc[4][4] = {};
    const u16* ga = A + (long long)m0 * K;
    const u16* gb = Bt + (long long)n0 * K;

    for (int k0 = 0; k0 < K; k0 += 32) {
#pragma unroll
        for (int rr = 0; rr < 2; ++rr) {
            int c = tid + rr * 256;
            int row = c >> 2, kc = c & 3;
            async16(ga + (long long)row * K + k0 + kc * 8, (char*)As + c * 16);
            async16(gb + (long long)row * K + k0 + kc * 8, (char*)Bs + c * 16);
        }
        __syncthreads();
        bf16x8 af[4], bfv[4];
#pragma unroll
        for (int mt = 0; mt < 4; ++mt)
            af[mt] = *(const bf16x8*)(As + (wm + mt * 16 + l16) * 32 + quad * 8);
#pragma unroll
        for (int nt = 0; nt < 4; ++nt)
            bfv[nt] = *(const bf16x8*)(Bs + (wn + nt * 16 + l16) * 32 + quad * 8);
#pragma unroll
        for (int mt = 0; mt < 4; ++mt)
#pragma unroll
            for (int nt = 0; nt < 4; ++nt)
                acc[mt][nt] = __builtin_amdgcn_mfma_f32_16x16x32_bf16(af[mt], bfv[nt],
                                                                      acc[mt][nt], 0, 0, 0);
        __syncthreads();
    }

#pragma unroll
    for (int mt = 0; mt < 4; ++mt) {
#pragma unroll
        for (int nt = 0; nt < 4; ++nt) {
            int col = n0 + wn + nt * 16 + l16;
            float bvs = bias[col];
#pragma unroll
            for (int r = 0; r < 4; ++r) {
                int row = m0 + wm + mt * 16 + quad * 4 + r;
                Cout[(long long)row * N + col] = acc[mt][nt][r] + bvs;
            }
        }
    }
}

// ---------------- Flash attention: 128-row Q-tiles, XCD-swizzled, dbuf LDS, exp2 --------
// grid = 512; xcd = bid&7 owns heads xcd*8..xcd*8+8 -> K/V L2-resident per XCD
__global__ __launch_bounds__(256, 2) void flash_attn(const u16* __restrict__ Q,
                                                     const u16* __restrict__ K,
                                                     const u16* __restrict__ VT,
                                                     u16* __restrict__ Y) {
    int bid = blockIdx.x;
    // XCD-aware swizzle: consecutive blockIdx round-robin over 8 XCDs; keep all 8
    // q-tile blocks of one head on the same XCD so K/V stay in that XCD's L2.
    int xcd = bid & 7;
    int idx = bid >> 3;              // 0..63
    int pi = idx & 7;                // q-tile pair index within head
    int hg = xcd * 8 + (idx >> 3);   // global head 0..63
    int b = hg >> 5, h = hg & 31;
    int tid = threadIdx.x;
    int w = tid >> 6, lane = tid & 63, quad = lane >> 4, l16 = lane & 15;

    __shared__ __align__(16) u16 Kl[2][64 * 64];     // [kc][d], chunk-xor-swizzled
    __shared__ __align__(16) u16 Vl[2][64 * 64];     // [d][kc], chunk-xor-swizzled
    __shared__ __align__(16) u16 Pl[4][32 * 64];     // per-wave [q][kc], xor-swizzled

    const u16* kbase = K + ((long long)(b * S_LEN)) * DM + h * DHEAD;
    const u16* vbase = VT + ((long long)((b * NHEAD + h) * DHEAD)) * S_LEN;

    // two-stage pipeline: regs hold next tile, LDS holds committed tile
    bf16x8 kpre[2], vpre[2];
    int c0 = tid, c1 = tid + 256;
    int row0 = c0 >> 3, lc0 = (c0 & 7) ^ (row0 & 7);
    int row1 = c1 >> 3, lc1 = (c1 & 7) ^ (row1 & 7);

    // preload k-tile 0
    kpre[0] = *(const bf16x8*)(kbase + (long long)row0 * DM + lc0 * 8);
    vpre[0] = *(const bf16x8*)(vbase + (long long)row0 * S_LEN + lc0 * 8);
    kpre[1] = *(const bf16x8*)(kbase + (long long)row1 * DM + lc1 * 8);
    vpre[1] = *(const bf16x8*)(vbase + (long long)row1 * S_LEN + lc1 * 8);

    int it = 0;   // running tile counter -> LDS buffer parity (continuous across reps)
#pragma unroll 1
    for (int rep = 0; rep < 2; ++rep) {
        int qt = rep ? 15 - pi : pi;            // 128-row q-tile index
        // Q fragments for both 16-row sub-tiles
        bf16x8 aq[2][2];
#pragma unroll
        for (int sub = 0; sub < 2; ++sub) {
            int qrow = qt * 128 + w * 32 + sub * 16 + l16;
            const u16* qp = Q + ((long long)(b * S_LEN + qrow)) * DM + h * DHEAD + quad * 8;
            aq[sub][0] = *(const bf16x8*)(qp);
            aq[sub][1] = *(const bf16x8*)(qp + 32);
        }

        f32x4 o[2][4] = {};
        float m_r[2] = {-__builtin_inff(), -__builtin_inff()};
        float l_r[2] = {0.f, 0.f};

        int kts = 2 * qt + 2;
#pragma unroll 1
        for (int kt = 0; kt < kts; ++kt) {
            u16* Kb_ = Kl[it & 1];
            u16* Vb_ = Vl[it & 1];
            // commit prefetched tile to this iteration's buffer
            *(bf16x8*)((char*)Kb_ + c0 * 16) = kpre[0];
            *(bf16x8*)((char*)Vb_ + c0 * 16) = vpre[0];
            *(bf16x8*)((char*)Kb_ + c1 * 16) = kpre[1];
            *(bf16x8*)((char*)Vb_ + c1 * 16) = vpre[1];
            // issue global prefetch of the next tile (tile 0 of next rep at the seam)
            {
                int nk0 = (kt + 1 < kts ? kt + 1 : 0) * 64;
                kpre[0] = *(const bf16x8*)(kbase + (long long)(nk0 + row0) * DM + lc0 * 8);
                vpre[0] = *(const bf16x8*)(vbase + (long long)row0 * S_LEN + nk0 + lc0 * 8);
                kpre[1] = *(const bf16x8*)(kbase + (long long)(nk0 + row1) * DM + lc1 * 8);
                vpre[1] = *(const bf16x8*)(vbase + (long long)row1 * S_LEN + nk0 + lc1 * 8);
            }
            __syncthreads();     // tile visible; prev-buffer readers are past this fence

            // ---- K fragments (shared by both q-subtiles) ----
            bf16x8 ak0[4], ak1[4];
#pragma unroll
            for (int nt = 0; nt < 4; ++nt) {
                int row = nt * 16 + l16;
                ak0[nt] = *(const bf16x8*)(Kb_ + row * 64 + (quad ^ (row & 7)) * 8);
                ak1[nt] = *(const bf16x8*)(Kb_ + row * 64 + ((quad + 4) ^ (row & 7)) * 8);
            }

            bf16x8 bp[2][2];
            u16* pw = &Pl[w][0];
#pragma unroll
            for (int sub = 0; sub < 2; ++sub) {
                // ---- S^T = K Q^T : rows kc (regs), cols q = l16 ----
                f32x4 s[4];
#pragma unroll
                for (int nt = 0; nt < 4; ++nt) {
                    f32x4 a = {};
                    a = __builtin_amdgcn_mfma_f32_16x16x32_bf16(ak0[nt], aq[sub][0], a, 0, 0, 0);
                    a = __builtin_amdgcn_mfma_f32_16x16x32_bf16(ak1[nt], aq[sub][1], a, 0, 0, 0);
                    s[nt] = a;
                }
                // causal mask (only the last two k-tiles can touch the diagonal)
                if (kt >= 2 * qt) {
                    int qg = qt * 128 + w * 32 + sub * 16 + l16;
#pragma unroll
                    for (int nt = 0; nt < 4; ++nt) {
#pragma unroll
                        for (int r = 0; r < 4; ++r) {
                            int kg = kt * 64 + nt * 16 + quad * 4 + r;
                            if (kg > qg) s[nt][r] = -__builtin_inff();
                        }
                    }
                }
                // ---- per-lane online softmax in exp2 domain ----
                float mx = s[0][0];
#pragma unroll
                for (int nt = 0; nt < 4; ++nt)
#pragma unroll
                    for (int r = 0; r < 4; ++r) mx = fmaxf(mx, s[nt][r]);
                mx = fmaxf(mx, __shfl_xor(mx, 16, 64));
                mx = fmaxf(mx, __shfl_xor(mx, 32, 64));
                float mnew = fmaxf(m_r[sub], mx);
                float alpha = fexp2(m_r[sub] - mnew);
                m_r[sub] = mnew;
#pragma unroll
                for (int nt = 0; nt < 4; ++nt)
#pragma unroll
                    for (int r = 0; r < 4; ++r) s[nt][r] = fexp2(s[nt][r] - mnew);
                float sum = 0.f;
#pragma unroll
                for (int nt = 0; nt < 4; ++nt)
#pragma unroll
                    for (int r = 0; r < 4; ++r) sum += s[nt][r];
                sum += __shfl_xor(sum, 16, 64);
                sum += __shfl_xor(sum, 32, 64);
                l_r[sub] = l_r[sub] * alpha + sum;
#pragma unroll
                for (int dt = 0; dt < 4; ++dt)
#pragma unroll
                    for (int r = 0; r < 4; ++r) o[sub][dt][r] *= alpha;

                // ---- P[q][kc] pack, xor-swizzled, per-wave, no barrier ----
                int prow = sub * 16 + l16;
#pragma unroll
                for (int nt = 0; nt < 4; ++nt) {
                    ushort4 pk;
                    pk.x = f2bf(s[nt][0]); pk.y = f2bf(s[nt][1]);
                    pk.z = f2bf(s[nt][2]); pk.w = f2bf(s[nt][3]);
                    int chunk = (nt * 2 + (quad >> 1)) ^ (l16 & 7);
                    *(ushort4*)(pw + prow * 64 + chunk * 8 + (quad & 1) * 4) = pk;
                }
                bp[sub][0] = *(const bf16x8*)(pw + prow * 64 + (quad ^ (l16 & 7)) * 8);
                bp[sub][1] = *(const bf16x8*)(pw + prow * 64 + ((quad + 4) ^ (l16 & 7)) * 8);
            }

            // ---- V fragments (shared) + PV MFMAs ----
#pragma unroll
            for (int dt = 0; dt < 4; ++dt) {
                int row = dt * 16 + l16;
                bf16x8 av0 = *(const bf16x8*)(Vb_ + row * 64 + (quad ^ (row & 7)) * 8);
                bf16x8 av1 = *(const bf16x8*)(Vb_ + row * 64 + ((quad + 4) ^ (row & 7)) * 8);
#pragma unroll
                for (int sub = 0; sub < 2; ++sub) {
                    o[sub][dt] = __builtin_amdgcn_mfma_f32_16x16x32_bf16(av0, bp[sub][0],
                                                                         o[sub][dt], 0, 0, 0);
                    o[sub][dt] = __builtin_amdgcn_mfma_f32_16x16x32_bf16(av1, bp[sub][1],
                                                                         o[sub][dt], 0, 0, 0);
                }
            }
            ++it;
        }

        // ---- epilogue: o[sub][dt] holds O^T[d][q=l16]; l per-lane ----
#pragma unroll
        for (int sub = 0; sub < 2; ++sub) {
            float inv_l = 1.f / l_r[sub];
            u16* yp = Y + ((long long)(b * S_LEN + qt * 128 + w * 32 + sub * 16 + l16)) * DM
                      + h * DHEAD;
#pragma unroll
            for (int dt = 0; dt < 4; ++dt) {
                ushort4 yk;
                yk.x = f2bf(o[sub][dt][0] * inv_l);
                yk.y = f2bf(o[sub][dt][1] * inv_l);
                yk.z = f2bf(o[sub][dt][2] * inv_l);
                yk.w = f2bf(o[sub][dt][3] * inv_l);
                *(ushort4*)(yp + dt * 16 + quad * 4) = yk;
            }
        }
    }
}

extern "C" void kernel_launch(void* const* d_in, const int* in_sizes, int n_in,
                              void* d_out, int out_size, void* d_ws, size_t ws_size,
                              hipStream_t stream) {
    const float* x  = (const float*)d_in[0];
    const float* Wq = (const float*)d_in[1];
    const float* bq = (const float*)d_in[2];
    const float* Wk = (const float*)d_in[3];
    const float* bk = (const float*)d_in[4];
    const float* Wv = (const float*)d_in[5];
    const float* bv = (const float*)d_in[6];
    const float* Wo = (const float*)d_in[7];
    const float* bo = (const float*)d_in[8];

    const long long M = 2LL * S_LEN;          // 4096

    char* ws = (char*)d_ws;
    u16* xb   = (u16*)(ws);                        // 16 MB
    u16* Wqkv = (u16*)(ws + 16 * 1024 * 1024);     // 24 MB
    u16* Wob  = (u16*)(ws + 40 * 1024 * 1024);     // 8 MB
    u16* Qb   = (u16*)(ws + 48 * 1024 * 1024);     // 16 MB each
    u16* Kb   = (u16*)(ws + 64 * 1024 * 1024);
    u16* Vb   = (u16*)(ws + 80 * 1024 * 1024);     // raw V (bias added)
    u16* Yb   = (u16*)(ws + 96 * 1024 * 1024);
    u16* VTb  = (u16*)(ws + 112 * 1024 * 1024);    // sigmoid(V)^T [b,h,d,s]

    cast_all<<<24576, 256, 0, stream>>>(x, Wq, Wk, Wv, Wo, xb, Wqkv, Wob);

    gemm_qkv8<<<384, 512, 0, stream>>>(xb, Wqkv, bq, bk, bv, Qb, Kb, Vb);

    rope_vsig<<<34816, 256, 0, stream>>>(Qb, Kb, Vb, VTb);

    flash_attn<<<2 * NHEAD * 8, 256, 0, stream>>>(Qb, Kb, VTb, Yb);

    dim3 gg(32, 16);
    gemm_bt_f32<<<gg, 256, 0, stream>>>(Yb, Wob, bo, (float*)d_out, (int)M, DM, DM);
}

// Round 5
// 424.380 us; speedup vs baseline: 1.1420x; 1.1420x over previous
//
#include <hip/hip_runtime.h>

typedef unsigned short u16;
typedef float f32x4 __attribute__((ext_vector_type(4)));
typedef __bf16 bf16x8 __attribute__((ext_vector_type(8)));

#define S_LEN 2048
#define DM 2048
#define NHEAD 32
#define DHEAD 64

__device__ __forceinline__ u16 f2bf(float f) {
    __bf16 b = (__bf16)f;
    return __builtin_bit_cast(u16, b);
}
__device__ __forceinline__ float bf2f(u16 u) {
    return (float)__builtin_bit_cast(__bf16, u);
}
// async global->LDS, 16B per lane. LDS dest must be wave-uniform base + lane*16.
__device__ __forceinline__ void async16(const void* g, void* l) {
    __builtin_amdgcn_global_load_lds(
        (const __attribute__((address_space(1))) unsigned int*)g,
        (__attribute__((address_space(3))) unsigned int*)l, 16, 0, 0);
}
// hardware sin/cos: v_sin/v_cos take revolutions; fract-reduce first (ISA §3)
__device__ __forceinline__ void fast_sincos(float th, float* s, float* c) {
    float rev = th * 0.15915494309189535f;   // 1/(2*pi)
    rev = rev - floorf(rev);
    *s = __builtin_amdgcn_sinf(rev);
    *c = __builtin_amdgcn_cosf(rev);
}
__device__ __forceinline__ float fexp2(float x) { return __builtin_amdgcn_exp2f(x); }

// ---------------- fused cast f32 -> bf16 for x + 4 weights (one dispatch) ----------------
__global__ __launch_bounds__(256) void cast_all(const float* __restrict__ x,
                                                const float* __restrict__ Wq,
                                                const float* __restrict__ Wk,
                                                const float* __restrict__ Wv,
                                                const float* __restrict__ Wo,
                                                u16* __restrict__ xb,
                                                u16* __restrict__ Wqkv,
                                                u16* __restrict__ Wob) {
    int bid = blockIdx.x;
    const float* src;
    u16* dst;
    long long off;
    if (bid < 8192)       { src = x;  dst = xb;             off = (long long)bid * 1024; }
    else if (bid < 12288) { src = Wq; dst = Wqkv;           off = (long long)(bid - 8192) * 1024; }
    else if (bid < 16384) { src = Wk; dst = Wqkv + 4194304; off = (long long)(bid - 12288) * 1024; }
    else if (bid < 20480) { src = Wv; dst = Wqkv + 8388608; off = (long long)(bid - 16384) * 1024; }
    else                  { src = Wo; dst = Wob;            off = (long long)(bid - 20480) * 1024; }
    long long i = off + threadIdx.x * 4;
    float4 f = *(const float4*)(src + i);
    ushort4 v;
    v.x = f2bf(f.x); v.y = f2bf(f.y); v.z = f2bf(f.z); v.w = f2bf(f.w);
    *(ushort4*)(dst + i) = v;
}

// ---------------- merged QKV GEMM (R0-proven 128x128 structure) + FUSED epilogue --------
// A[4096][2048] x Wqkv[6144][2048]^T.
// Epilogue fusion replaces the old rope_vsig pass entirely:
//   sel 0/1 (Q/K): RoPE applied in f32 on acc+bias. Column pairing (j, j+32) within a
//     head is acc[mt][nt] <-> acc[mt][nt+2] (cols differ by exactly 32), same rows.
//     Q additionally scaled by 1/8*log2(e) (flash_attn works in exp2 domain).
//   sel 2 (V): sigmoid(acc+bias), written TRANSPOSED to VT[b,h,d,s]; each lane's 4
//     consecutive rows form one ushort4 along s -> transpose free in the store.
__global__ __launch_bounds__(256) void gemm_qkv(const u16* __restrict__ A,
                                                const u16* __restrict__ Bt,
                                                const float* __restrict__ bq,
                                                const float* __restrict__ bk,
                                                const float* __restrict__ bv,
                                                u16* __restrict__ Qo, u16* __restrict__ Ko,
                                                u16* __restrict__ VT, int M, int K) {
    __shared__ __align__(16) u16 As[128 * 32];
    __shared__ __align__(16) u16 Bs[128 * 32];
    int tid = threadIdx.x;
    int w = tid >> 6, lane = tid & 63, quad = lane >> 4, l16 = lane & 15;
    int m0 = blockIdx.x * 128;
    int n0 = blockIdx.y * 128;       // 0..6143
    int sel = n0 >> 11;
    int nloc = n0 & 2047;
    const float* bias = sel == 0 ? bq : (sel == 1 ? bk : bv);
    int wm = (w & 1) * 64, wn = (w >> 1) * 64;

    f32x4 acc[4][4] = {};
    const u16* ga = A + (long long)m0 * K;
    const u16* gb = Bt + (long long)n0 * K;

    for (int k0 = 0; k0 < K; k0 += 32) {
#pragma unroll
        for (int rr = 0; rr < 2; ++rr) {
            int c = tid + rr * 256;
            int row = c >> 2, kc = c & 3;
            async16(ga + (long long)row * K + k0 + kc * 8, (char*)As + c * 16);
            async16(gb + (long long)row * K + k0 + kc * 8, (char*)Bs + c * 16);
        }
        __syncthreads();
        bf16x8 af[4], bfv[4];
#pragma unroll
        for (int mt = 0; mt < 4; ++mt)
            af[mt] = *(const bf16x8*)(As + (wm + mt * 16 + l16) * 32 + quad * 8);
#pragma unroll
        for (int nt = 0; nt < 4; ++nt)
            bfv[nt] = *(const bf16x8*)(Bs + (wn + nt * 16 + l16) * 32 + quad * 8);
#pragma unroll
        for (int mt = 0; mt < 4; ++mt)
#pragma unroll
            for (int nt = 0; nt < 4; ++nt)
                acc[mt][nt] = __builtin_amdgcn_mfma_f32_16x16x32_bf16(af[mt], bfv[nt],
                                                                      acc[mt][nt], 0, 0, 0);
        __syncthreads();
    }

    if (sel < 2) {
        // ---- fused RoPE epilogue for Q (scaled) / K ----
        u16* out = sel == 0 ? Qo : Ko;
        float scale = sel == 0 ? 0.18033688011112042f : 1.0f;  // Q: 1/8 * log2(e)
        float invf[2];
        invf[0] = __expf(-(float)l16 * 0.28782313662425575f);          // ln(1e4)/32
        invf[1] = __expf(-(float)(16 + l16) * 0.28782313662425575f);
#pragma unroll
        for (int mt = 0; mt < 4; ++mt) {
#pragma unroll
            for (int nt = 0; nt < 2; ++nt) {
                int col1 = nloc + wn + nt * 16 + l16;   // j = nt*16+l16 in [0,32)
                int col2 = col1 + 32;                   // partner j+32 -> acc[mt][nt+2]
                float b1 = bias[col1], b2 = bias[col2];
#pragma unroll
                for (int r = 0; r < 4; ++r) {
                    int row = m0 + wm + mt * 16 + quad * 4 + r;
                    int s = row & (S_LEN - 1);
                    float sn, cs;
                    fast_sincos((float)s * invf[nt], &sn, &cs);
                    float x1 = acc[mt][nt][r] + b1;
                    float x2 = acc[mt][nt + 2][r] + b2;
                    out[(long long)row * 2048 + col1] = f2bf((x1 * cs - x2 * sn) * scale);
                    out[(long long)row * 2048 + col2] = f2bf((x2 * cs + x1 * sn) * scale);
                }
            }
        }
    } else {
        // ---- fused sigmoid + transpose epilogue for V -> VT[b,h,d,s] ----
#pragma unroll
        for (int mt = 0; mt < 4; ++mt) {
#pragma unroll
            for (int nt = 0; nt < 4; ++nt) {
                int col = nloc + wn + nt * 16 + l16;
                int h = col >> 6, d = col & 63;
                float bvs = bias[col];
                int row0 = m0 + wm + mt * 16 + quad * 4;
                int b = row0 >> 11, s0 = row0 & (S_LEN - 1);
                ushort4 pk;
                pk.x = f2bf(1.f / (1.f + __expf(-(acc[mt][nt][0] + bvs))));
                pk.y = f2bf(1.f / (1.f + __expf(-(acc[mt][nt][1] + bvs))));
                pk.z = f2bf(1.f / (1.f + __expf(-(acc[mt][nt][2] + bvs))));
                pk.w = f2bf(1.f / (1.f + __expf(-(acc[mt][nt][3] + bvs))));
                *(ushort4*)(VT + ((long long)((b * NHEAD + h) * DHEAD + d)) * S_LEN + s0) = pk;
            }
        }
    }
}

// ---------------- GEMM: C[M][N] = A[M][K] * Bt[N][K]^T + bias (f32 out) ----------------
__global__ __launch_bounds__(256) void gemm_bt_f32(const u16* __restrict__ A,
                                                   const u16* __restrict__ Bt,
                                                   const float* __restrict__ bias,
                                                   float* __restrict__ Cout,
                                                   int M, int N, int K) {
    __shared__ __align__(16) u16 As[128 * 32];
    __shared__ __align__(16) u16 Bs[128 * 32];
    int tid = threadIdx.x;
    int w = tid >> 6, lane = tid & 63, quad = lane >> 4, l16 = lane & 15;
    int m0 = blockIdx.x * 128;
    int n0 = blockIdx.y * 128;
    int wm = (w & 1) * 64, wn = (w >> 1) * 64;

    f32x4 acc[4][4] = {};
    const u16* ga = A + (long long)m0 * K;
    const u16* gb = Bt + (long long)n0 * K;

    for (int k0 = 0; k0 < K; k0 += 32) {
#pragma unroll
        for (int rr = 0; rr < 2; ++rr) {
            int c = tid + rr * 256;
            int row = c >> 2, kc = c & 3;
            async16(ga + (long long)row * K + k0 + kc * 8, (char*)As + c * 16);
            async16(gb + (long long)row * K + k0 + kc * 8, (char*)Bs + c * 16);
        }
        __syncthreads();
        bf16x8 af[4], bfv[4];
#pragma unroll
        for (int mt = 0; mt < 4; ++mt)
            af[mt] = *(const bf16x8*)(As + (wm + mt * 16 + l16) * 32 + quad * 8);
#pragma unroll
        for (int nt = 0; nt < 4; ++nt)
            bfv[nt] = *(const bf16x8*)(Bs + (wn + nt * 16 + l16) * 32 + quad * 8);
#pragma unroll
        for (int mt = 0; mt < 4; ++mt)
#pragma unroll
            for (int nt = 0; nt < 4; ++nt)
                acc[mt][nt] = __builtin_amdgcn_mfma_f32_16x16x32_bf16(af[mt], bfv[nt],
                                                                      acc[mt][nt], 0, 0, 0);
        __syncthreads();
    }

#pragma unroll
    for (int mt = 0; mt < 4; ++mt) {
#pragma unroll
        for (int nt = 0; nt < 4; ++nt) {
            int col = n0 + wn + nt * 16 + l16;
            float bvs = bias[col];
#pragma unroll
            for (int r = 0; r < 4; ++r) {
                int row = m0 + wm + mt * 16 + quad * 4 + r;
                Cout[(long long)row * N + col] = acc[mt][nt][r] + bvs;
            }
        }
    }
}

// ---------------- Flash attention: 128-row Q-tiles, XCD-swizzled, dbuf LDS, exp2 --------
// grid = 512; xcd = bid&7 owns heads xcd*8..xcd*8+8 -> K/V L2-resident per XCD
__global__ __launch_bounds__(256, 2) void flash_attn(const u16* __restrict__ Q,
                                                     const u16* __restrict__ K,
                                                     const u16* __restrict__ VT,
                                                     u16* __restrict__ Y) {
    int bid = blockIdx.x;
    // XCD-aware swizzle: consecutive blockIdx round-robin over 8 XCDs; keep all 8
    // q-tile blocks of one head on the same XCD so K/V stay in that XCD's L2.
    int xcd = bid & 7;
    int idx = bid >> 3;              // 0..63
    int pi = idx & 7;                // q-tile pair index within head
    int hg = xcd * 8 + (idx >> 3);   // global head 0..63
    int b = hg >> 5, h = hg & 31;
    int tid = threadIdx.x;
    int w = tid >> 6, lane = tid & 63, quad = lane >> 4, l16 = lane & 15;

    __shared__ __align__(16) u16 Kl[2][64 * 64];     // [kc][d], chunk-xor-swizzled
    __shared__ __align__(16) u16 Vl[2][64 * 64];     // [d][kc], chunk-xor-swizzled
    __shared__ __align__(16) u16 Pl[4][32 * 64];     // per-wave [q][kc], xor-swizzled

    const u16* kbase = K + ((long long)(b * S_LEN)) * DM + h * DHEAD;
    const u16* vbase = VT + ((long long)((b * NHEAD + h) * DHEAD)) * S_LEN;

    // two-stage pipeline: regs hold next tile, LDS holds committed tile
    bf16x8 kpre[2], vpre[2];
    int c0 = tid, c1 = tid + 256;
    int row0 = c0 >> 3, lc0 = (c0 & 7) ^ (row0 & 7);
    int row1 = c1 >> 3, lc1 = (c1 & 7) ^ (row1 & 7);

    // preload k-tile 0
    kpre[0] = *(const bf16x8*)(kbase + (long long)row0 * DM + lc0 * 8);
    vpre[0] = *(const bf16x8*)(vbase + (long long)row0 * S_LEN + lc0 * 8);
    kpre[1] = *(const bf16x8*)(kbase + (long long)row1 * DM + lc1 * 8);
    vpre[1] = *(const bf16x8*)(vbase + (long long)row1 * S_LEN + lc1 * 8);

    int it = 0;   // running tile counter -> LDS buffer parity (continuous across reps)
#pragma unroll 1
    for (int rep = 0; rep < 2; ++rep) {
        int qt = rep ? 15 - pi : pi;            // 128-row q-tile index
        // Q fragments for both 16-row sub-tiles
        bf16x8 aq[2][2];
#pragma unroll
        for (int sub = 0; sub < 2; ++sub) {
            int qrow = qt * 128 + w * 32 + sub * 16 + l16;
            const u16* qp = Q + ((long long)(b * S_LEN + qrow)) * DM + h * DHEAD + quad * 8;
            aq[sub][0] = *(const bf16x8*)(qp);
            aq[sub][1] = *(const bf16x8*)(qp + 32);
        }

        f32x4 o[2][4] = {};
        float m_r[2] = {-__builtin_inff(), -__builtin_inff()};
        float l_r[2] = {0.f, 0.f};

        int kts = 2 * qt + 2;
#pragma unroll 1
        for (int kt = 0; kt < kts; ++kt) {
            u16* Kb_ = Kl[it & 1];
            u16* Vb_ = Vl[it & 1];
            // commit prefetched tile to this iteration's buffer
            *(bf16x8*)((char*)Kb_ + c0 * 16) = kpre[0];
            *(bf16x8*)((char*)Vb_ + c0 * 16) = vpre[0];
            *(bf16x8*)((char*)Kb_ + c1 * 16) = kpre[1];
            *(bf16x8*)((char*)Vb_ + c1 * 16) = vpre[1];
            // issue global prefetch of the next tile (tile 0 of next rep at the seam)
            {
                int nk0 = (kt + 1 < kts ? kt + 1 : 0) * 64;
                kpre[0] = *(const bf16x8*)(kbase + (long long)(nk0 + row0) * DM + lc0 * 8);
                vpre[0] = *(const bf16x8*)(vbase + (long long)row0 * S_LEN + nk0 + lc0 * 8);
                kpre[1] = *(const bf16x8*)(kbase + (long long)(nk0 + row1) * DM + lc1 * 8);
                vpre[1] = *(const bf16x8*)(vbase + (long long)row1 * S_LEN + nk0 + lc1 * 8);
            }
            __syncthreads();     // tile visible; prev-buffer readers are past this fence

            // ---- K fragments (shared by both q-subtiles) ----
            bf16x8 ak0[4], ak1[4];
#pragma unroll
            for (int nt = 0; nt < 4; ++nt) {
                int row = nt * 16 + l16;
                ak0[nt] = *(const bf16x8*)(Kb_ + row * 64 + (quad ^ (row & 7)) * 8);
                ak1[nt] = *(const bf16x8*)(Kb_ + row * 64 + ((quad + 4) ^ (row & 7)) * 8);
            }

            bf16x8 bp[2][2];
            u16* pw = &Pl[w][0];
#pragma unroll
            for (int sub = 0; sub < 2; ++sub) {
                // ---- S^T = K Q^T : rows kc (regs), cols q = l16 ----
                f32x4 s[4];
#pragma unroll
                for (int nt = 0; nt < 4; ++nt) {
                    f32x4 a = {};
                    a = __builtin_amdgcn_mfma_f32_16x16x32_bf16(ak0[nt], aq[sub][0], a, 0, 0, 0);
                    a = __builtin_amdgcn_mfma_f32_16x16x32_bf16(ak1[nt], aq[sub][1], a, 0, 0, 0);
                    s[nt] = a;
                }
                // causal mask (only the last two k-tiles can touch the diagonal)
                if (kt >= 2 * qt) {
                    int qg = qt * 128 + w * 32 + sub * 16 + l16;
#pragma unroll
                    for (int nt = 0; nt < 4; ++nt) {
#pragma unroll
                        for (int r = 0; r < 4; ++r) {
                            int kg = kt * 64 + nt * 16 + quad * 4 + r;
                            if (kg > qg) s[nt][r] = -__builtin_inff();
                        }
                    }
                }
                // ---- per-lane online softmax in exp2 domain ----
                float mx = s[0][0];
#pragma unroll
                for (int nt = 0; nt < 4; ++nt)
#pragma unroll
                    for (int r = 0; r < 4; ++r) mx = fmaxf(mx, s[nt][r]);
                mx = fmaxf(mx, __shfl_xor(mx, 16, 64));
                mx = fmaxf(mx, __shfl_xor(mx, 32, 64));
                float mnew = fmaxf(m_r[sub], mx);
                float alpha = fexp2(m_r[sub] - mnew);
                m_r[sub] = mnew;
#pragma unroll
                for (int nt = 0; nt < 4; ++nt)
#pragma unroll
                    for (int r = 0; r < 4; ++r) s[nt][r] = fexp2(s[nt][r] - mnew);
                float sum = 0.f;
#pragma unroll
                for (int nt = 0; nt < 4; ++nt)
#pragma unroll
                    for (int r = 0; r < 4; ++r) sum += s[nt][r];
                sum += __shfl_xor(sum, 16, 64);
                sum += __shfl_xor(sum, 32, 64);
                l_r[sub] = l_r[sub] * alpha + sum;
#pragma unroll
                for (int dt = 0; dt < 4; ++dt)
#pragma unroll
                    for (int r = 0; r < 4; ++r) o[sub][dt][r] *= alpha;

                // ---- P[q][kc] pack, xor-swizzled, per-wave, no barrier ----
                int prow = sub * 16 + l16;
#pragma unroll
                for (int nt = 0; nt < 4; ++nt) {
                    ushort4 pk;
                    pk.x = f2bf(s[nt][0]); pk.y = f2bf(s[nt][1]);
                    pk.z = f2bf(s[nt][2]); pk.w = f2bf(s[nt][3]);
                    int chunk = (nt * 2 + (quad >> 1)) ^ (l16 & 7);
                    *(ushort4*)(pw + prow * 64 + chunk * 8 + (quad & 1) * 4) = pk;
                }
                bp[sub][0] = *(const bf16x8*)(pw + prow * 64 + (quad ^ (l16 & 7)) * 8);
                bp[sub][1] = *(const bf16x8*)(pw + prow * 64 + ((quad + 4) ^ (l16 & 7)) * 8);
            }

            // ---- V fragments (shared) + PV MFMAs ----
#pragma unroll
            for (int dt = 0; dt < 4; ++dt) {
                int row = dt * 16 + l16;
                bf16x8 av0 = *(const bf16x8*)(Vb_ + row * 64 + (quad ^ (row & 7)) * 8);
                bf16x8 av1 = *(const bf16x8*)(Vb_ + row * 64 + ((quad + 4) ^ (row & 7)) * 8);
#pragma unroll
                for (int sub = 0; sub < 2; ++sub) {
                    o[sub][dt] = __builtin_amdgcn_mfma_f32_16x16x32_bf16(av0, bp[sub][0],
                                                                         o[sub][dt], 0, 0, 0);
                    o[sub][dt] = __builtin_amdgcn_mfma_f32_16x16x32_bf16(av1, bp[sub][1],
                                                                         o[sub][dt], 0, 0, 0);
                }
            }
            ++it;
        }

        // ---- epilogue: o[sub][dt] holds O^T[d][q=l16]; l per-lane ----
#pragma unroll
        for (int sub = 0; sub < 2; ++sub) {
            float inv_l = 1.f / l_r[sub];
            u16* yp = Y + ((long long)(b * S_LEN + qt * 128 + w * 32 + sub * 16 + l16)) * DM
                      + h * DHEAD;
#pragma unroll
            for (int dt = 0; dt < 4; ++dt) {
                ushort4 yk;
                yk.x = f2bf(o[sub][dt][0] * inv_l);
                yk.y = f2bf(o[sub][dt][1] * inv_l);
                yk.z = f2bf(o[sub][dt][2] * inv_l);
                yk.w = f2bf(o[sub][dt][3] * inv_l);
                *(ushort4*)(yp + dt * 16 + quad * 4) = yk;
            }
        }
    }
}

extern "C" void kernel_launch(void* const* d_in, const int* in_sizes, int n_in,
                              void* d_out, int out_size, void* d_ws, size_t ws_size,
                              hipStream_t stream) {
    const float* x  = (const float*)d_in[0];
    const float* Wq = (const float*)d_in[1];
    const float* bq = (const float*)d_in[2];
    const float* Wk = (const float*)d_in[3];
    const float* bk = (const float*)d_in[4];
    const float* Wv = (const float*)d_in[5];
    const float* bv = (const float*)d_in[6];
    const float* Wo = (const float*)d_in[7];
    const float* bo = (const float*)d_in[8];

    const long long M = 2LL * S_LEN;          // 4096

    char* ws = (char*)d_ws;
    u16* xb   = (u16*)(ws);                        // 16 MB
    u16* Wqkv = (u16*)(ws + 16 * 1024 * 1024);     // 24 MB
    u16* Wob  = (u16*)(ws + 40 * 1024 * 1024);     // 8 MB
    u16* Qb   = (u16*)(ws + 48 * 1024 * 1024);     // 16 MB each
    u16* Kb   = (u16*)(ws + 64 * 1024 * 1024);
    u16* Yb   = (u16*)(ws + 96 * 1024 * 1024);
    u16* VTb  = (u16*)(ws + 112 * 1024 * 1024);    // sigmoid(V)^T [b,h,d,s]

    cast_all<<<24576, 256, 0, stream>>>(x, Wq, Wk, Wv, Wo, xb, Wqkv, Wob);

    dim3 gqkv(32, 48);
    gemm_qkv<<<gqkv, 256, 0, stream>>>(xb, Wqkv, bq, bk, bv, Qb, Kb, VTb, (int)M, DM);

    flash_attn<<<2 * NHEAD * 8, 256, 0, stream>>>(Qb, Kb, VTb, Yb);

    dim3 gg(32, 16);
    gemm_bt_f32<<<gg, 256, 0, stream>>>(Yb, Wob, bo, (float*)d_out, (int)M, DM, DM);
}

// Round 6
// 420.300 us; speedup vs baseline: 1.1531x; 1.0097x over previous
//
#include <hip/hip_runtime.h>

typedef unsigned short u16;
typedef float f32x4 __attribute__((ext_vector_type(4)));
typedef __bf16 bf16x8 __attribute__((ext_vector_type(8)));

#define S_LEN 2048
#define DM 2048
#define NHEAD 32
#define DHEAD 64

__device__ __forceinline__ u16 f2bf(float f) {
    __bf16 b = (__bf16)f;
    return __builtin_bit_cast(u16, b);
}
__device__ __forceinline__ float bf2f(u16 u) {
    return (float)__builtin_bit_cast(__bf16, u);
}
// async global->LDS, 16B per lane. LDS dest must be wave-uniform base + lane*16.
__device__ __forceinline__ void async16(const void* g, void* l) {
    __builtin_amdgcn_global_load_lds(
        (const __attribute__((address_space(1))) unsigned int*)g,
        (__attribute__((address_space(3))) unsigned int*)l, 16, 0, 0);
}
// hardware sin/cos: v_sin/v_cos take revolutions; fract-reduce first (ISA §3)
__device__ __forceinline__ void fast_sincos(float th, float* s, float* c) {
    float rev = th * 0.15915494309189535f;   // 1/(2*pi)
    rev = rev - floorf(rev);
    *s = __builtin_amdgcn_sinf(rev);
    *c = __builtin_amdgcn_cosf(rev);
}
__device__ __forceinline__ float fexp2(float x) { return __builtin_amdgcn_exp2f(x); }

// ---------------- fused cast f32 -> bf16 for x + 4 weights (one dispatch) ----------------
__global__ __launch_bounds__(256) void cast_all(const float* __restrict__ x,
                                                const float* __restrict__ Wq,
                                                const float* __restrict__ Wk,
                                                const float* __restrict__ Wv,
                                                const float* __restrict__ Wo,
                                                u16* __restrict__ xb,
                                                u16* __restrict__ Wqkv,
                                                u16* __restrict__ Wob) {
    int bid = blockIdx.x;
    const float* src;
    u16* dst;
    long long off;
    if (bid < 8192)       { src = x;  dst = xb;             off = (long long)bid * 1024; }
    else if (bid < 12288) { src = Wq; dst = Wqkv;           off = (long long)(bid - 8192) * 1024; }
    else if (bid < 16384) { src = Wk; dst = Wqkv + 4194304; off = (long long)(bid - 12288) * 1024; }
    else if (bid < 20480) { src = Wv; dst = Wqkv + 8388608; off = (long long)(bid - 16384) * 1024; }
    else                  { src = Wo; dst = Wob;            off = (long long)(bid - 20480) * 1024; }
    long long i = off + threadIdx.x * 4;
    float4 f = *(const float4*)(src + i);
    ushort4 v;
    v.x = f2bf(f.x); v.y = f2bf(f.y); v.z = f2bf(f.z); v.w = f2bf(f.w);
    *(ushort4*)(dst + i) = v;
}

// ---------------- merged QKV GEMM (R0-proven 128x128 structure) + FUSED epilogue --------
// A[4096][2048] x Wqkv[6144][2048]^T.
// Epilogue fusion replaces the old rope_vsig pass:
//   sel 0/1 (Q/K): RoPE in f32 on acc+bias; pairing (j, j+32) = acc[mt][nt]<->acc[mt][nt+2].
//   sel 2 (V): sigmoid(acc+bias) written TRANSPOSED to VT[b,h,d,s].
// R5 lesson: epilogue invariants (__expf invf, scale, cols) were LICM-hoisted ABOVE the
// K-loop -> +16 VGPR live across the loop (76->92), K-loop codegen perturbed, 153->193us.
// R6 fix: anti-LICM fences — copies of sel/l16 pinned by empty asm AFTER the loop; all
// epilogue-only values derive from the fenced copies, so they cannot be hoisted.
__global__ __launch_bounds__(256) void gemm_qkv(const u16* __restrict__ A,
                                                const u16* __restrict__ Bt,
                                                const float* __restrict__ bq,
                                                const float* __restrict__ bk,
                                                const float* __restrict__ bv,
                                                u16* __restrict__ Qo, u16* __restrict__ Ko,
                                                u16* __restrict__ VT, int M, int K) {
    __shared__ __align__(16) u16 As[128 * 32];
    __shared__ __align__(16) u16 Bs[128 * 32];
    int tid = threadIdx.x;
    int w = tid >> 6, lane = tid & 63, quad = lane >> 4, l16 = lane & 15;
    int m0 = blockIdx.x * 128;
    int n0 = blockIdx.y * 128;       // 0..6143
    int sel = n0 >> 11;
    int nloc = n0 & 2047;
    const float* bias = sel == 0 ? bq : (sel == 1 ? bk : bv);
    int wm = (w & 1) * 64, wn = (w >> 1) * 64;

    f32x4 acc[4][4] = {};
    const u16* ga = A + (long long)m0 * K;
    const u16* gb = Bt + (long long)n0 * K;

    for (int k0 = 0; k0 < K; k0 += 32) {
#pragma unroll
        for (int rr = 0; rr < 2; ++rr) {
            int c = tid + rr * 256;
            int row = c >> 2, kc = c & 3;
            async16(ga + (long long)row * K + k0 + kc * 8, (char*)As + c * 16);
            async16(gb + (long long)row * K + k0 + kc * 8, (char*)Bs + c * 16);
        }
        __syncthreads();
        bf16x8 af[4], bfv[4];
#pragma unroll
        for (int mt = 0; mt < 4; ++mt)
            af[mt] = *(const bf16x8*)(As + (wm + mt * 16 + l16) * 32 + quad * 8);
#pragma unroll
        for (int nt = 0; nt < 4; ++nt)
            bfv[nt] = *(const bf16x8*)(Bs + (wn + nt * 16 + l16) * 32 + quad * 8);
#pragma unroll
        for (int mt = 0; mt < 4; ++mt)
#pragma unroll
            for (int nt = 0; nt < 4; ++nt)
                acc[mt][nt] = __builtin_amdgcn_mfma_f32_16x16x32_bf16(af[mt], bfv[nt],
                                                                      acc[mt][nt], 0, 0, 0);
        __syncthreads();
    }

    // ---- anti-LICM fences: epilogue-only invariants must derive from these copies ----
    int sel_f = sel;
    asm volatile("" : "+s"(sel_f));
    int l16_f = l16;
    asm volatile("" : "+v"(l16_f));

    if (sel_f < 2) {
        // ---- fused RoPE epilogue for Q (scaled) / K ----
        u16* out = sel_f == 0 ? Qo : Ko;
        float scale = sel_f == 0 ? 0.18033688011112042f : 1.0f;  // Q: 1/8 * log2(e)
        float invf[2];
        invf[0] = __expf(-(float)l16_f * 0.28782313662425575f);          // ln(1e4)/32
        invf[1] = __expf(-(float)(16 + l16_f) * 0.28782313662425575f);
#pragma unroll
        for (int mt = 0; mt < 4; ++mt) {
#pragma unroll
            for (int nt = 0; nt < 2; ++nt) {
                int col1 = nloc + wn + nt * 16 + l16_f;  // j = nt*16+l16 in [0,32)
                int col2 = col1 + 32;                    // partner j+32 -> acc[mt][nt+2]
                float b1 = bias[col1], b2 = bias[col2];
#pragma unroll
                for (int r = 0; r < 4; ++r) {
                    int row = m0 + wm + mt * 16 + quad * 4 + r;
                    int s = row & (S_LEN - 1);
                    float sn, cs;
                    fast_sincos((float)s * invf[nt], &sn, &cs);
                    float x1 = acc[mt][nt][r] + b1;
                    float x2 = acc[mt][nt + 2][r] + b2;
                    out[(long long)row * 2048 + col1] = f2bf((x1 * cs - x2 * sn) * scale);
                    out[(long long)row * 2048 + col2] = f2bf((x2 * cs + x1 * sn) * scale);
                }
            }
        }
    } else {
        // ---- fused sigmoid + transpose epilogue for V -> VT[b,h,d,s] ----
#pragma unroll
        for (int mt = 0; mt < 4; ++mt) {
#pragma unroll
            for (int nt = 0; nt < 4; ++nt) {
                int col = nloc + wn + nt * 16 + l16_f;
                int h = col >> 6, d = col & 63;
                float bvs = bias[col];
                int row0 = m0 + wm + mt * 16 + quad * 4;
                int b = row0 >> 11, s0 = row0 & (S_LEN - 1);
                ushort4 pk;
                pk.x = f2bf(1.f / (1.f + __expf(-(acc[mt][nt][0] + bvs))));
                pk.y = f2bf(1.f / (1.f + __expf(-(acc[mt][nt][1] + bvs))));
                pk.z = f2bf(1.f / (1.f + __expf(-(acc[mt][nt][2] + bvs))));
                pk.w = f2bf(1.f / (1.f + __expf(-(acc[mt][nt][3] + bvs))));
                *(ushort4*)(VT + ((long long)((b * NHEAD + h) * DHEAD + d)) * S_LEN + s0) = pk;
            }
        }
    }
}

// ---------------- GEMM: C[M][N] = A[M][K] * Bt[N][K]^T + bias (f32 out) ----------------
__global__ __launch_bounds__(256) void gemm_bt_f32(const u16* __restrict__ A,
                                                   const u16* __restrict__ Bt,
                                                   const float* __restrict__ bias,
                                                   float* __restrict__ Cout,
                                                   int M, int N, int K) {
    __shared__ __align__(16) u16 As[128 * 32];
    __shared__ __align__(16) u16 Bs[128 * 32];
    int tid = threadIdx.x;
    int w = tid >> 6, lane = tid & 63, quad = lane >> 4, l16 = lane & 15;
    int m0 = blockIdx.x * 128;
    int n0 = blockIdx.y * 128;
    int wm = (w & 1) * 64, wn = (w >> 1) * 64;

    f32x4 acc[4][4] = {};
    const u16* ga = A + (long long)m0 * K;
    const u16* gb = Bt + (long long)n0 * K;

    for (int k0 = 0; k0 < K; k0 += 32) {
#pragma unroll
        for (int rr = 0; rr < 2; ++rr) {
            int c = tid + rr * 256;
            int row = c >> 2, kc = c & 3;
            async16(ga + (long long)row * K + k0 + kc * 8, (char*)As + c * 16);
            async16(gb + (long long)row * K + k0 + kc * 8, (char*)Bs + c * 16);
        }
        __syncthreads();
        bf16x8 af[4], bfv[4];
#pragma unroll
        for (int mt = 0; mt < 4; ++mt)
            af[mt] = *(const bf16x8*)(As + (wm + mt * 16 + l16) * 32 + quad * 8);
#pragma unroll
        for (int nt = 0; nt < 4; ++nt)
            bfv[nt] = *(const bf16x8*)(Bs + (wn + nt * 16 + l16) * 32 + quad * 8);
#pragma unroll
        for (int mt = 0; mt < 4; ++mt)
#pragma unroll
            for (int nt = 0; nt < 4; ++nt)
                acc[mt][nt] = __builtin_amdgcn_mfma_f32_16x16x32_bf16(af[mt], bfv[nt],
                                                                      acc[mt][nt], 0, 0, 0);
        __syncthreads();
    }

#pragma unroll
    for (int mt = 0; mt < 4; ++mt) {
#pragma unroll
        for (int nt = 0; nt < 4; ++nt) {
            int col = n0 + wn + nt * 16 + l16;
            float bvs = bias[col];
#pragma unroll
            for (int r = 0; r < 4; ++r) {
                int row = m0 + wm + mt * 16 + quad * 4 + r;
                Cout[(long long)row * N + col] = acc[mt][nt][r] + bvs;
            }
        }
    }
}

// ---------------- Flash attention: 128-row Q-tiles, XCD-swizzled, dbuf LDS, exp2 --------
// grid = 512; xcd = bid&7 owns heads xcd*8..xcd*8+8 -> K/V L2-resident per XCD
__global__ __launch_bounds__(256, 2) void flash_attn(const u16* __restrict__ Q,
                                                     const u16* __restrict__ K,
                                                     const u16* __restrict__ VT,
                                                     u16* __restrict__ Y) {
    int bid = blockIdx.x;
    // XCD-aware swizzle: consecutive blockIdx round-robin over 8 XCDs; keep all 8
    // q-tile blocks of one head on the same XCD so K/V stay in that XCD's L2.
    int xcd = bid & 7;
    int idx = bid >> 3;              // 0..63
    int pi = idx & 7;                // q-tile pair index within head
    int hg = xcd * 8 + (idx >> 3);   // global head 0..63
    int b = hg >> 5, h = hg & 31;
    int tid = threadIdx.x;
    int w = tid >> 6, lane = tid & 63, quad = lane >> 4, l16 = lane & 15;

    __shared__ __align__(16) u16 Kl[2][64 * 64];     // [kc][d], chunk-xor-swizzled
    __shared__ __align__(16) u16 Vl[2][64 * 64];     // [d][kc], chunk-xor-swizzled
    __shared__ __align__(16) u16 Pl[4][32 * 64];     // per-wave [q][kc], xor-swizzled

    const u16* kbase = K + ((long long)(b * S_LEN)) * DM + h * DHEAD;
    const u16* vbase = VT + ((long long)((b * NHEAD + h) * DHEAD)) * S_LEN;

    // two-stage pipeline: regs hold next tile, LDS holds committed tile
    bf16x8 kpre[2], vpre[2];
    int c0 = tid, c1 = tid + 256;
    int row0 = c0 >> 3, lc0 = (c0 & 7) ^ (row0 & 7);
    int row1 = c1 >> 3, lc1 = (c1 & 7) ^ (row1 & 7);

    // preload k-tile 0
    kpre[0] = *(const bf16x8*)(kbase + (long long)row0 * DM + lc0 * 8);
    vpre[0] = *(const bf16x8*)(vbase + (long long)row0 * S_LEN + lc0 * 8);
    kpre[1] = *(const bf16x8*)(kbase + (long long)row1 * DM + lc1 * 8);
    vpre[1] = *(const bf16x8*)(vbase + (long long)row1 * S_LEN + lc1 * 8);

    int it = 0;   // running tile counter -> LDS buffer parity (continuous across reps)
#pragma unroll 1
    for (int rep = 0; rep < 2; ++rep) {
        int qt = rep ? 15 - pi : pi;            // 128-row q-tile index
        // Q fragments for both 16-row sub-tiles
        bf16x8 aq[2][2];
#pragma unroll
        for (int sub = 0; sub < 2; ++sub) {
            int qrow = qt * 128 + w * 32 + sub * 16 + l16;
            const u16* qp = Q + ((long long)(b * S_LEN + qrow)) * DM + h * DHEAD + quad * 8;
            aq[sub][0] = *(const bf16x8*)(qp);
            aq[sub][1] = *(const bf16x8*)(qp + 32);
        }

        f32x4 o[2][4] = {};
        float m_r[2] = {-__builtin_inff(), -__builtin_inff()};
        float l_r[2] = {0.f, 0.f};

        int kts = 2 * qt + 2;
#pragma unroll 1
        for (int kt = 0; kt < kts; ++kt) {
            u16* Kb_ = Kl[it & 1];
            u16* Vb_ = Vl[it & 1];
            // commit prefetched tile to this iteration's buffer
            *(bf16x8*)((char*)Kb_ + c0 * 16) = kpre[0];
            *(bf16x8*)((char*)Vb_ + c0 * 16) = vpre[0];
            *(bf16x8*)((char*)Kb_ + c1 * 16) = kpre[1];
            *(bf16x8*)((char*)Vb_ + c1 * 16) = vpre[1];
            // issue global prefetch of the next tile (tile 0 of next rep at the seam)
            {
                int nk0 = (kt + 1 < kts ? kt + 1 : 0) * 64;
                kpre[0] = *(const bf16x8*)(kbase + (long long)(nk0 + row0) * DM + lc0 * 8);
                vpre[0] = *(const bf16x8*)(vbase + (long long)row0 * S_LEN + nk0 + lc0 * 8);
                kpre[1] = *(const bf16x8*)(kbase + (long long)(nk0 + row1) * DM + lc1 * 8);
                vpre[1] = *(const bf16x8*)(vbase + (long long)row1 * S_LEN + nk0 + lc1 * 8);
            }
            __syncthreads();     // tile visible; prev-buffer readers are past this fence

            // ---- K fragments (shared by both q-subtiles) ----
            bf16x8 ak0[4], ak1[4];
#pragma unroll
            for (int nt = 0; nt < 4; ++nt) {
                int row = nt * 16 + l16;
                ak0[nt] = *(const bf16x8*)(Kb_ + row * 64 + (quad ^ (row & 7)) * 8);
                ak1[nt] = *(const bf16x8*)(Kb_ + row * 64 + ((quad + 4) ^ (row & 7)) * 8);
            }

            bf16x8 bp[2][2];
            u16* pw = &Pl[w][0];
#pragma unroll
            for (int sub = 0; sub < 2; ++sub) {
                // ---- S^T = K Q^T : rows kc (regs), cols q = l16 ----
                f32x4 s[4];
#pragma unroll
                for (int nt = 0; nt < 4; ++nt) {
                    f32x4 a = {};
                    a = __builtin_amdgcn_mfma_f32_16x16x32_bf16(ak0[nt], aq[sub][0], a, 0, 0, 0);
                    a = __builtin_amdgcn_mfma_f32_16x16x32_bf16(ak1[nt], aq[sub][1], a, 0, 0, 0);
                    s[nt] = a;
                }
                // causal mask (only the last two k-tiles can touch the diagonal)
                if (kt >= 2 * qt) {
                    int qg = qt * 128 + w * 32 + sub * 16 + l16;
#pragma unroll
                    for (int nt = 0; nt < 4; ++nt) {
#pragma unroll
                        for (int r = 0; r < 4; ++r) {
                            int kg = kt * 64 + nt * 16 + quad * 4 + r;
                            if (kg > qg) s[nt][r] = -__builtin_inff();
                        }
                    }
                }
                // ---- per-lane online softmax in exp2 domain ----
                float mx = s[0][0];
#pragma unroll
                for (int nt = 0; nt < 4; ++nt)
#pragma unroll
                    for (int r = 0; r < 4; ++r) mx = fmaxf(mx, s[nt][r]);
                mx = fmaxf(mx, __shfl_xor(mx, 16, 64));
                mx = fmaxf(mx, __shfl_xor(mx, 32, 64));
                float mnew = fmaxf(m_r[sub], mx);
                float alpha = fexp2(m_r[sub] - mnew);
                m_r[sub] = mnew;
#pragma unroll
                for (int nt = 0; nt < 4; ++nt)
#pragma unroll
                    for (int r = 0; r < 4; ++r) s[nt][r] = fexp2(s[nt][r] - mnew);
                float sum = 0.f;
#pragma unroll
                for (int nt = 0; nt < 4; ++nt)
#pragma unroll
                    for (int r = 0; r < 4; ++r) sum += s[nt][r];
                sum += __shfl_xor(sum, 16, 64);
                sum += __shfl_xor(sum, 32, 64);
                l_r[sub] = l_r[sub] * alpha + sum;
#pragma unroll
                for (int dt = 0; dt < 4; ++dt)
#pragma unroll
                    for (int r = 0; r < 4; ++r) o[sub][dt][r] *= alpha;

                // ---- P[q][kc] pack, xor-swizzled, per-wave, no barrier ----
                int prow = sub * 16 + l16;
#pragma unroll
                for (int nt = 0; nt < 4; ++nt) {
                    ushort4 pk;
                    pk.x = f2bf(s[nt][0]); pk.y = f2bf(s[nt][1]);
                    pk.z = f2bf(s[nt][2]); pk.w = f2bf(s[nt][3]);
                    int chunk = (nt * 2 + (quad >> 1)) ^ (l16 & 7);
                    *(ushort4*)(pw + prow * 64 + chunk * 8 + (quad & 1) * 4) = pk;
                }
                bp[sub][0] = *(const bf16x8*)(pw + prow * 64 + (quad ^ (l16 & 7)) * 8);
                bp[sub][1] = *(const bf16x8*)(pw + prow * 64 + ((quad + 4) ^ (l16 & 7)) * 8);
            }

            // ---- V fragments (shared) + PV MFMAs ----
#pragma unroll
            for (int dt = 0; dt < 4; ++dt) {
                int row = dt * 16 + l16;
                bf16x8 av0 = *(const bf16x8*)(Vb_ + row * 64 + (quad ^ (row & 7)) * 8);
                bf16x8 av1 = *(const bf16x8*)(Vb_ + row * 64 + ((quad + 4) ^ (row & 7)) * 8);
#pragma unroll
                for (int sub = 0; sub < 2; ++sub) {
                    o[sub][dt] = __builtin_amdgcn_mfma_f32_16x16x32_bf16(av0, bp[sub][0],
                                                                         o[sub][dt], 0, 0, 0);
                    o[sub][dt] = __builtin_amdgcn_mfma_f32_16x16x32_bf16(av1, bp[sub][1],
                                                                         o[sub][dt], 0, 0, 0);
                }
            }
            ++it;
        }

        // ---- epilogue: o[sub][dt] holds O^T[d][q=l16]; l per-lane ----
#pragma unroll
        for (int sub = 0; sub < 2; ++sub) {
            float inv_l = 1.f / l_r[sub];
            u16* yp = Y + ((long long)(b * S_LEN + qt * 128 + w * 32 + sub * 16 + l16)) * DM
                      + h * DHEAD;
#pragma unroll
            for (int dt = 0; dt < 4; ++dt) {
                ushort4 yk;
                yk.x = f2bf(o[sub][dt][0] * inv_l);
                yk.y = f2bf(o[sub][dt][1] * inv_l);
                yk.z = f2bf(o[sub][dt][2] * inv_l);
                yk.w = f2bf(o[sub][dt][3] * inv_l);
                *(ushort4*)(yp + dt * 16 + quad * 4) = yk;
            }
        }
    }
}

extern "C" void kernel_launch(void* const* d_in, const int* in_sizes, int n_in,
                              void* d_out, int out_size, void* d_ws, size_t ws_size,
                              hipStream_t stream) {
    const float* x  = (const float*)d_in[0];
    const float* Wq = (const float*)d_in[1];
    const float* bq = (const float*)d_in[2];
    const float* Wk = (const float*)d_in[3];
    const float* bk = (const float*)d_in[4];
    const float* Wv = (const float*)d_in[5];
    const float* bv = (const float*)d_in[6];
    const float* Wo = (const float*)d_in[7];
    const float* bo = (const float*)d_in[8];

    const long long M = 2LL * S_LEN;          // 4096

    char* ws = (char*)d_ws;
    u16* xb   = (u16*)(ws);                        // 16 MB
    u16* Wqkv = (u16*)(ws + 16 * 1024 * 1024);     // 24 MB
    u16* Wob  = (u16*)(ws + 40 * 1024 * 1024);     // 8 MB
    u16* Qb   = (u16*)(ws + 48 * 1024 * 1024);     // 16 MB each
    u16* Kb   = (u16*)(ws + 64 * 1024 * 1024);
    u16* Yb   = (u16*)(ws + 96 * 1024 * 1024);
    u16* VTb  = (u16*)(ws + 112 * 1024 * 1024);    // sigmoid(V)^T [b,h,d,s]

    cast_all<<<24576, 256, 0, stream>>>(x, Wq, Wk, Wv, Wo, xb, Wqkv, Wob);

    dim3 gqkv(32, 48);
    gemm_qkv<<<gqkv, 256, 0, stream>>>(xb, Wqkv, bq, bk, bv, Qb, Kb, VTb, (int)M, DM);

    flash_attn<<<2 * NHEAD * 8, 256, 0, stream>>>(Qb, Kb, VTb, Yb);

    dim3 gg(32, 16);
    gemm_bt_f32<<<gg, 256, 0, stream>>>(Yb, Wob, bo, (float*)d_out, (int)M, DM, DM);
}